// Round 15
// baseline (459.223 us; speedup 1.0000x reference)
//
#include <hip/hip_runtime.h>
#include <hip/hip_bf16.h>

#define T_TOK 4096
#define H_DIM 1024
#define E_EXP 32
#define TOPK 4
#define CAP 1024
#define PAIRS (T_TOK*TOPK)

typedef __attribute__((ext_vector_type(8))) short short8v;
typedef __attribute__((ext_vector_type(4))) float f32x4;
typedef unsigned long long u64;
typedef unsigned short ushort;

__device__ __forceinline__ float bf16_bits_to_f32(ushort h) {
    return __uint_as_float(((unsigned)h) << 16);
}
__device__ __forceinline__ unsigned bf16r(float f) {
    unsigned u = __float_as_uint(f);
    return ((u + 0x7fffu + ((u >> 16) & 1u)) >> 16) & 0xffffu;
}
__device__ __forceinline__ unsigned cvt2(float a, float b) {
    unsigned r;
    asm("v_cvt_pk_bf16_f32 %0, %1, %2" : "=v"(r) : "v"(a), "v"(b));
    return r;
}
__device__ __forceinline__ u64 pk4(float a, float b, float c, float d) {
    return (u64)cvt2(a, b) | ((u64)cvt2(c, d) << 32);
}

#define GLD16(gsrc, ldst) \
    __builtin_amdgcn_global_load_lds( \
        (const __attribute__((address_space(1))) unsigned*)(gsrc), \
        (__attribute__((address_space(3))) unsigned*)(ldst), 16, 0, 0)

#define WAIT_VM(N)   asm volatile("s_waitcnt vmcnt(" #N ")" ::: "memory")
#define WAIT_VMLG(N) asm volatile("s_waitcnt vmcnt(" #N ") lgkmcnt(0)" ::: "memory")
#define WAIT_LG()    asm volatile("s_waitcnt lgkmcnt(0)" ::: "memory")
#define SCHEDB()     __builtin_amdgcn_sched_barrier(0)
#define BARRIER()    __builtin_amdgcn_s_barrier()

// ---------------- router: 8 tokens/block, single rw pass ----------------
__global__ __launch_bounds__(256) void router_kernel(
    const float* __restrict__ x, const float* __restrict__ rw,
    const float* __restrict__ rb, float* __restrict__ scores,
    int* __restrict__ flat_e, float* __restrict__ flat_w)
{
    __shared__ float xs[8][H_DIM];   // 32 KB
    __shared__ float lg[8][E_EXP];
    const int t0 = blockIdx.x * 8;
    const int tid = threadIdx.x;

    for (int i = tid; i < 2048; i += 256) {
        int row = i >> 8, c4 = i & 255;
        *(float4*)&xs[row][c4 * 4] =
            *(const float4*)(x + (size_t)(t0 + row) * H_DIM + c4 * 4);
    }
    __syncthreads();

    const int e = tid >> 3, l8 = tid & 7;
    float part[8];
    #pragma unroll
    for (int tt = 0; tt < 8; ++tt) part[tt] = 0.f;
    const float* wrow = rw + (size_t)e * H_DIM;
    for (int h = l8; h < H_DIM; h += 8) {
        float w = wrow[h];
        #pragma unroll
        for (int tt = 0; tt < 8; ++tt) part[tt] = fmaf(xs[tt][h], w, part[tt]);
    }
    #pragma unroll
    for (int tt = 0; tt < 8; ++tt) {
        float v = part[tt];
        v += __shfl_xor(v, 1);
        v += __shfl_xor(v, 2);
        v += __shfl_xor(v, 4);
        if (l8 == 0) lg[tt][e] = v + rb[e];
    }
    __syncthreads();

    if (tid < 8) {
        const int tt = tid, t = t0 + tt;
        unsigned used = 0;
        float bv[TOPK]; int bi[TOPK];
        #pragma unroll
        for (int j = 0; j < TOPK; j++) {
            float best = -1e30f; int bid = -1;
            for (int q = 0; q < E_EXP; q++) {
                if (used & (1u << q)) continue;
                if (lg[tt][q] > best) { best = lg[tt][q]; bid = q; }
            }
            used |= 1u << bid;
            bv[j] = best; bi[j] = bid;
        }
        const float m = bv[0];
        float s = 0.f; float w[TOPK];
        #pragma unroll
        for (int j = 0; j < TOPK; j++) { w[j] = expf(bv[j] - m); s += w[j]; }
        const float inv = 1.f / s;
        #pragma unroll
        for (int j = 0; j < TOPK; j++) w[j] *= inv;
        for (int q = 0; q < E_EXP; ++q) {
            float v = 0.f;
            #pragma unroll
            for (int j = 0; j < TOPK; j++) if (bi[j] == q) v = w[j];
            scores[(size_t)t * E_EXP + q] = v;
        }
        #pragma unroll
        for (int j = 0; j < TOPK; j++) {
            flat_e[t * TOPK + j] = bi[j];
            flat_w[t * TOPK + j] = w[j];
        }
    }
}

// ---------------- deterministic rank scan ----------------
__global__ __launch_bounds__(256) void scan_kernel(
    const int* __restrict__ flat_e, const float* __restrict__ flat_w,
    int* __restrict__ slot_token, float* __restrict__ slot_w,
    int* __restrict__ pair_slot, int* __restrict__ counts)
{
    __shared__ int cnt[256 * E_EXP];
    const int tid = threadIdx.x;
    for (int e = 0; e < E_EXP; e++) cnt[tid * E_EXP + e] = 0;
    __syncthreads();
    const int base = tid * (PAIRS / 256);
    for (int i = 0; i < PAIRS / 256; i++) {
        int e = flat_e[base + i];
        cnt[tid * E_EXP + e]++;
    }
    __syncthreads();
    if (tid < E_EXP) {
        int run = 0;
        for (int i = 0; i < 256; i++) {
            int idx = i * E_EXP + tid;
            int v = cnt[idx];
            cnt[idx] = run;
            run += v;
        }
        counts[tid] = min(run, CAP);
    }
    __syncthreads();
    for (int i = 0; i < PAIRS / 256; i++) {
        int p = base + i;
        int e = flat_e[p];
        int r = cnt[tid * E_EXP + e]++;
        if (r < CAP) {
            slot_token[e * CAP + r] = p >> 2;
            slot_w[e * CAP + r] = flat_w[p];
            pair_slot[p] = r;
        } else {
            pair_slot[p] = -1;
        }
    }
}

// ---------------- stage tokens: gather x -> granule-packed bf16 xbuf ----------------
__global__ __launch_bounds__(256) void stage_tokens(
    const float* __restrict__ x, const int* __restrict__ slot_token,
    const int* __restrict__ counts, char* __restrict__ xbuf)
{
    const int e = blockIdx.y, rt = blockIdx.x;
    const int n = counts[e];
    const int row0 = rt * 128;
    if (row0 >= n) return;
    const int rows_here = min(128, n - row0);
    const int lane = threadIdx.x & 63, wv = threadIdx.x >> 6;
    char* tb = xbuf + ((size_t)(e * 8 + rt)) * 262144;

    for (int r = wv; r < rows_here; r += 4) {
        const float* xr = x + (size_t)slot_token[e * CAP + row0 + r] * H_DIM;
        const int s = (r >> 1) & 3;
        #pragma unroll
        for (int half = 0; half < 2; ++half) {
            int gi = half * 64 + lane;
            float4 a = *(const float4*)(xr + gi * 8);
            float4 b = *(const float4*)(xr + gi * 8 + 4);
            uint4 w;
            w.x = cvt2(a.x, a.y); w.y = cvt2(a.z, a.w);
            w.z = cvt2(b.x, b.y); w.w = cvt2(b.z, b.w);
            int t = gi >> 2, kq = gi & 3;
            *(uint4*)(tb + (size_t)t * 8192 + r * 64 + ((kq ^ s) * 16)) = w;
        }
    }
}

// ---------------- gate_up MFMA GEMM: A depth-3 LDS, B depth-4 regs, 1 wait/iter ----------------
__global__ __launch_bounds__(256, 3) void gateup_mfma(
    const char* __restrict__ xbuf, const float* __restrict__ wgu,
    const float* __restrict__ gub, const int* __restrict__ counts,
    char* __restrict__ act)
{
    const int lin = blockIdx.x;
    const int xcd = lin & 7, slot = lin >> 3;
    const int gg = (slot >> 3) * 8 + xcd;
    const int rt = slot & 7;
    const int e = gg >> 4, ct = gg & 15;

    const int n = counts[e];
    const int row0 = rt * 128;
    if (row0 >= n) return;
    const int rows_here = min(128, n - row0);
    const int c0f = ct * 64, c0gu = ct * 128;

    __shared__ char AsB[3][8192];
    __shared__ char BgB[2][4096];
    __shared__ char BuB[2][4096];

    const int tid = threadIdx.x;
    const int lane = tid & 63, wid = tid >> 6;
    const int wr = wid >> 1, wc = wid & 1;
    const int l15 = lane & 15, l4 = lane >> 4;
    const int kq = tid >> 5;      // 0..7 (4-row K group)
    const int p2 = tid & 31;      // gu-col quad index

    const char* xtile = xbuf + ((size_t)(e * 8 + rt)) * 262144;

    f32x4 accg[4][2], accu[4][2];
    #pragma unroll
    for (int m = 0; m < 4; m++)
        #pragma unroll
        for (int j = 0; j < 2; j++) { accg[m][j] = (f32x4)0.f; accu[m][j] = (f32x4)0.f; }

    float4 bvA[4], bvB[4], bvC[4], bvD[4];

#define GU_STAGE_A(BUF, T) { \
    const char* sa_ = xtile + (size_t)(T) * 8192 + tid * 16; \
    GLD16(sa_, AsB[BUF] + tid * 16); \
    GLD16(sa_ + 4096, AsB[BUF] + 4096 + tid * 16); }

#define GU_BLOAD(BV, T) { \
    const float* sb_ = wgu + ((size_t)e * 1024 + (T) * 32 + kq * 4) * 2048 + c0gu + 4 * p2; \
    BV[0] = *(const float4*)(sb_); \
    BV[1] = *(const float4*)(sb_ + 2048); \
    BV[2] = *(const float4*)(sb_ + 4096); \
    BV[3] = *(const float4*)(sb_ + 6144); }

#define GU_BPACK(BUF, BV) { \
    char* dg_ = BgB[BUF] + (kq >> 1) * 1024 + (2 * p2) * 16 + (kq & 1) * 8; \
    char* du_ = BuB[BUF] + (kq >> 1) * 1024 + (2 * p2) * 16 + (kq & 1) * 8; \
    *(u64*)dg_        = pk4(BV[0].x, BV[1].x, BV[2].x, BV[3].x); \
    *(u64*)(dg_ + 16) = pk4(BV[0].z, BV[1].z, BV[2].z, BV[3].z); \
    *(u64*)du_        = pk4(BV[0].y, BV[1].y, BV[2].y, BV[3].y); \
    *(u64*)(du_ + 16) = pk4(BV[0].w, BV[1].w, BV[2].w, BV[3].w); }

#define GU_COMPUTE(AC, BC) { \
    short8v afr[4]; \
    _Pragma("unroll") \
    for (int m = 0; m < 4; ++m) { \
        int row_ = wr * 64 + m * 16 + l15; \
        afr[m] = *(short8v*)(AsB[AC] + row_ * 64 + ((l4 ^ ((row_ >> 1) & 3)) * 16)); \
    } \
    __builtin_amdgcn_s_setprio(1); \
    _Pragma("unroll") \
    for (int j = 0; j < 2; ++j) { \
        int fl_ = wc * 32 + j * 16 + l15; \
        short8v bg8 = *(short8v*)(BgB[BC] + l4 * 1024 + fl_ * 16); \
        short8v bu8 = *(short8v*)(BuB[BC] + l4 * 1024 + fl_ * 16); \
        _Pragma("unroll") \
        for (int m = 0; m < 4; ++m) { \
            accg[m][j] = __builtin_amdgcn_mfma_f32_16x16x32_bf16(afr[m], bg8, accg[m][j], 0, 0, 0); \
            accu[m][j] = __builtin_amdgcn_mfma_f32_16x16x32_bf16(afr[m], bu8, accu[m][j], 0, 0, 0); \
        } \
    } \
    __builtin_amdgcn_s_setprio(0); }

    // prologue: issue A0[2] B0[4] B1[4] B2[4] A1[2] B3[4] = 20 outstanding
    GU_STAGE_A(0, 0);
    GU_BLOAD(bvA, 0);
    GU_BLOAD(bvB, 1);
    GU_BLOAD(bvC, 2);
    GU_STAGE_A(1, 1);
    GU_BLOAD(bvD, 3);
    WAIT_VM(14); SCHEDB();        // retire A0,B0
    GU_BPACK(0, bvA);
    WAIT_LG(); SCHEDB();
    BARRIER(); SCHEDB();

    // t = 0 (pipeline still filling: extra pre-pack wait)
    GU_STAGE_A(2, 2);
    GU_BLOAD(bvA, 4);
    GU_COMPUTE(0, 0); SCHEDB();
    WAIT_VM(16); SCHEDB();        // retire B1
    GU_BPACK(1, bvB);
    WAIT_VMLG(10); SCHEDB();      // retire B2,A1 -> {B3,A2,B4}
    BARRIER(); SCHEDB();

    // steady iters: issue A(t+2),B(t+4); compute t; pack B(t+1) (already retired); one wait
#define GU_ITS(T, AB, BS, AC, BC, PS, PB) { \
    GU_STAGE_A(AB, (T) + 2); \
    GU_BLOAD(BS, (T) + 4); \
    GU_COMPUTE(AC, BC); SCHEDB(); \
    GU_BPACK(PB, PS); \
    WAIT_VMLG(10); SCHEDB(); \
    BARRIER(); SCHEDB(); }

    GU_ITS(1, 0, bvB, 1, 1, bvC, 0)
    GU_ITS(2, 1, bvC, 2, 0, bvD, 1)
    GU_ITS(3, 2, bvD, 0, 1, bvA, 0)
    GU_ITS(4, 0, bvA, 1, 0, bvB, 1)
    GU_ITS(5, 1, bvB, 2, 1, bvC, 0)
    GU_ITS(6, 2, bvC, 0, 0, bvD, 1)
    GU_ITS(7, 0, bvD, 1, 1, bvA, 0)
    GU_ITS(8, 1, bvA, 2, 0, bvB, 1)
    GU_ITS(9, 2, bvB, 0, 1, bvC, 0)
    GU_ITS(10, 0, bvC, 1, 0, bvD, 1)
    GU_ITS(11, 1, bvD, 2, 1, bvA, 0)
    GU_ITS(12, 2, bvA, 0, 0, bvB, 1)
    GU_ITS(13, 0, bvB, 1, 1, bvC, 0)
    GU_ITS(14, 1, bvC, 2, 0, bvD, 1)
    GU_ITS(15, 2, bvD, 0, 1, bvA, 0)
    GU_ITS(16, 0, bvA, 1, 0, bvB, 1)
    GU_ITS(17, 1, bvB, 2, 1, bvC, 0)
    GU_ITS(18, 2, bvC, 0, 0, bvD, 1)
    GU_ITS(19, 0, bvD, 1, 1, bvA, 0)
    GU_ITS(20, 1, bvA, 2, 0, bvB, 1)
    GU_ITS(21, 2, bvB, 0, 1, bvC, 0)
    GU_ITS(22, 0, bvC, 1, 0, bvD, 1)
    GU_ITS(23, 1, bvD, 2, 1, bvA, 0)
    GU_ITS(24, 2, bvA, 0, 0, bvB, 1)
    GU_ITS(25, 0, bvB, 1, 1, bvC, 0)
    GU_ITS(26, 1, bvC, 2, 0, bvD, 1)
    GU_ITS(27, 2, bvD, 0, 1, bvA, 0)

    // tail
    GU_STAGE_A(0, 30);
    GU_COMPUTE(1, 0); SCHEDB();
    GU_BPACK(1, bvB);             // B29
    WAIT_VMLG(6); SCHEDB();
    BARRIER(); SCHEDB();

    GU_STAGE_A(1, 31);
    GU_COMPUTE(2, 1); SCHEDB();
    GU_BPACK(0, bvC);             // B30
    WAIT_VMLG(2); SCHEDB();
    BARRIER(); SCHEDB();

    GU_COMPUTE(0, 0); SCHEDB();
    GU_BPACK(1, bvD);             // B31
    WAIT_VMLG(0); SCHEDB();
    BARRIER(); SCHEDB();

    GU_COMPUTE(1, 1);

#undef GU_ITS
#undef GU_COMPUTE
#undef GU_BPACK
#undef GU_BLOAD
#undef GU_STAGE_A

    // epilogue: bias + clamp + GLU -> act (granule-packed, k-dim = f)
    char* atile = act + ((size_t)(e * 8 + rt)) * 262144;
    #pragma unroll
    for (int j = 0; j < 2; ++j) {
        int f = c0f + wc * 32 + j * 16 + l15;
        float bgb = gub[(size_t)e * 2048 + 2 * f];
        float bub = gub[(size_t)e * 2048 + 2 * f + 1];
        int tt = f >> 5, kq2 = (f & 31) >> 3, ke = f & 7;
        #pragma unroll
        for (int m = 0; m < 4; ++m) {
            int rbase = wr * 64 + m * 16 + l4 * 4;
            #pragma unroll
            for (int reg = 0; reg < 4; ++reg) {
                int r = rbase + reg;
                if (r >= rows_here) continue;
                float g = accg[m][j][reg] + bgb;
                float u = accu[m][j][reg] + bub;
                g = fminf(g, 7.0f);
                u = fminf(fmaxf(u, -7.0f), 7.0f);
                float glu = g / (1.0f + __expf(-1.702f * g));
                float a = (u + 1.0f) * glu;
                *(ushort*)(atile + (size_t)tt * 8192 + r * 64 +
                           ((kq2 ^ ((r >> 1) & 3)) * 16) + ke * 2) = (ushort)bf16r(a);
            }
        }
    }
}

// ---------------- down MFMA GEMM: A depth-3, B depth-3 -> eout (bf16) ----------------
__global__ __launch_bounds__(256, 3) void down_mfma(
    const char* __restrict__ act, const float* __restrict__ wd,
    const float* __restrict__ db, const int* __restrict__ counts,
    ushort* __restrict__ eout)
{
    const int lin = blockIdx.x;
    const int xcd = lin & 7, slot = lin >> 3;
    const int gg = (slot >> 3) * 8 + xcd;
    const int rt = slot & 7;
    const int e = gg >> 3, ct = gg & 7;

    const int n = counts[e];
    const int row0 = rt * 128;
    if (row0 >= n) return;
    const int rows_here = min(128, n - row0);
    const int c0 = ct * 128;

    __shared__ char AsB[3][8192];
    __shared__ char BsB[2][8192];

    const int tid = threadIdx.x;
    const int lane = tid & 63, wid = tid >> 6;
    const int wr = wid >> 1, wc = wid & 1;
    const int l15 = lane & 15, l4 = lane >> 4;
    const int kq = tid >> 5;      // 0..7
    const int p2 = tid & 31;      // n-col quad index

    const char* atile = act + ((size_t)(e * 8 + rt)) * 262144;

    f32x4 acc[4][4];
    #pragma unroll
    for (int m = 0; m < 4; m++)
        #pragma unroll
        for (int j = 0; j < 4; j++) acc[m][j] = (f32x4)0.f;

    float4 bv0[4], bv1[4], bv2[4];

#define DN_STAGE_A(BUF, T) { \
    const char* sa_ = atile + (size_t)(T) * 8192 + tid * 16; \
    GLD16(sa_, AsB[BUF] + tid * 16); \
    GLD16(sa_ + 4096, AsB[BUF] + 4096 + tid * 16); }

#define DN_BLOAD(BV, T) { \
    const float* sb_ = wd + ((size_t)e * 1024 + (T) * 32 + kq * 4) * 1024 + c0 + 4 * p2; \
    BV[0] = *(const float4*)(sb_); \
    BV[1] = *(const float4*)(sb_ + 1024); \
    BV[2] = *(const float4*)(sb_ + 2048); \
    BV[3] = *(const float4*)(sb_ + 3072); }

#define DN_BPACK(BUF, BV) { \
    char* d0_ = BsB[BUF] + (kq >> 1) * 2048 + (4 * p2) * 16 + (kq & 1) * 8; \
    *(u64*)d0_        = pk4(BV[0].x, BV[1].x, BV[2].x, BV[3].x); \
    *(u64*)(d0_ + 16) = pk4(BV[0].y, BV[1].y, BV[2].y, BV[3].y); \
    *(u64*)(d0_ + 32) = pk4(BV[0].z, BV[1].z, BV[2].z, BV[3].z); \
    *(u64*)(d0_ + 48) = pk4(BV[0].w, BV[1].w, BV[2].w, BV[3].w); }

#define DN_COMPUTE(AC, BC) { \
    short8v afr[4]; \
    _Pragma("unroll") \
    for (int m = 0; m < 4; ++m) { \
        int row_ = wr * 64 + m * 16 + l15; \
        afr[m] = *(short8v*)(AsB[AC] + row_ * 64 + ((l4 ^ ((row_ >> 1) & 3)) * 16)); \
    } \
    __builtin_amdgcn_s_setprio(1); \
    _Pragma("unroll") \
    for (int j = 0; j < 4; ++j) { \
        int nn_ = wc * 64 + j * 16 + l15; \
        short8v b8 = *(short8v*)(BsB[BC] + l4 * 2048 + nn_ * 16); \
        _Pragma("unroll") \
        for (int m = 0; m < 4; ++m) \
            acc[m][j] = __builtin_amdgcn_mfma_f32_16x16x32_bf16(afr[m], b8, acc[m][j], 0, 0, 0); \
    } \
    __builtin_amdgcn_s_setprio(0); }

    DN_STAGE_A(0, 0);
    DN_BLOAD(bv0, 0);
    DN_BLOAD(bv1, 1);
    DN_STAGE_A(1, 1);
    DN_BLOAD(bv2, 2);
    WAIT_VM(10); SCHEDB();
    DN_BPACK(0, bv0);
    WAIT_LG(); SCHEDB();
    BARRIER(); SCHEDB();

#define DN_IT(T, A2, LS, PS, AC, BC, BN) { \
    DN_STAGE_A(A2, (T) + 2); \
    DN_BLOAD(bv##LS, (T) + 3); \
    DN_COMPUTE(AC, BC); SCHEDB(); \
    WAIT_VM(12); SCHEDB(); \
    DN_BPACK(BN, bv##PS); \
    WAIT_VMLG(10); SCHEDB(); \
    BARRIER(); SCHEDB(); }

    for (int t6 = 0; t6 < 24; t6 += 6) {
        DN_IT(t6 + 0, 2, 0, 1, 0, 0, 1)
        DN_IT(t6 + 1, 0, 1, 2, 1, 1, 0)
        DN_IT(t6 + 2, 1, 2, 0, 2, 0, 1)
        DN_IT(t6 + 3, 2, 0, 1, 0, 1, 0)
        DN_IT(t6 + 4, 0, 1, 2, 1, 0, 1)
        DN_IT(t6 + 5, 1, 2, 0, 2, 1, 0)
    }
    DN_IT(24, 2, 0, 1, 0, 0, 1)
    DN_IT(25, 0, 1, 2, 1, 1, 0)
    DN_IT(26, 1, 2, 0, 2, 0, 1)
    DN_IT(27, 2, 0, 1, 0, 1, 0)
    DN_IT(28, 0, 1, 2, 1, 0, 1)
    // t = 29
    DN_STAGE_A(1, 31);
    DN_COMPUTE(2, 1); SCHEDB();
    WAIT_VM(8); SCHEDB();
    DN_BPACK(0, bv0);
    WAIT_VMLG(6); SCHEDB();
    BARRIER(); SCHEDB();
    // t = 30
    DN_COMPUTE(0, 0); SCHEDB();
    WAIT_VM(2); SCHEDB();
    DN_BPACK(1, bv1);
    WAIT_VMLG(0); SCHEDB();
    BARRIER(); SCHEDB();
    // t = 31
    DN_COMPUTE(1, 1);

#undef DN_IT
#undef DN_COMPUTE
#undef DN_BPACK
#undef DN_BLOAD
#undef DN_STAGE_A

    // epilogue: bias, store bf16 eout rows (streaming, no atomics)
    #pragma unroll
    for (int j = 0; j < 4; ++j) {
        int col = c0 + wc * 64 + j * 16 + l15;
        float bias = db[(size_t)e * H_DIM + col];
        #pragma unroll
        for (int m = 0; m < 4; ++m) {
            int rbase = wr * 64 + m * 16 + l4 * 4;
            #pragma unroll
            for (int reg = 0; reg < 4; ++reg) {
                int r = rbase + reg;
                if (r >= rows_here) continue;
                eout[((size_t)e * CAP + row0 + r) * H_DIM + col] =
                    (ushort)bf16r(acc[m][j][reg] + bias);
            }
        }
    }
}

// ---------------- finalize: out[t] = sum_k w_k * eout[e_k, slot_k] ----------------
__global__ __launch_bounds__(256) void finalize_kernel(
    const ushort* __restrict__ eout, const int* __restrict__ flat_e,
    const float* __restrict__ flat_w, const int* __restrict__ pair_slot,
    float* __restrict__ out)
{
    const int t = blockIdx.x;
    const int c = threadIdx.x * 4;
    float a0 = 0.f, a1 = 0.f, a2 = 0.f, a3 = 0.f;
    #pragma unroll
    for (int k = 0; k < TOPK; ++k) {
        int p = t * TOPK + k;
        int s = pair_slot[p];
        if (s < 0) continue;
        int e = flat_e[p];
        float w = flat_w[p];
        const ushort* row = eout + ((size_t)e * CAP + s) * H_DIM + c;
        ushort4 v = *(const ushort4*)row;
        a0 += w * bf16_bits_to_f32(v.x);
        a1 += w * bf16_bits_to_f32(v.y);
        a2 += w * bf16_bits_to_f32(v.z);
        a3 += w * bf16_bits_to_f32(v.w);
    }
    *(float4*)(out + (size_t)t * H_DIM + c) = make_float4(a0, a1, a2, a3);
}

extern "C" void kernel_launch(void* const* d_in, const int* in_sizes, int n_in,
                              void* d_out, int out_size, void* d_ws, size_t ws_size,
                              hipStream_t stream) {
    const float* x   = (const float*)d_in[0];
    const float* rw  = (const float*)d_in[1];
    const float* rb  = (const float*)d_in[2];
    const float* wgu = (const float*)d_in[3];
    const float* gub = (const float*)d_in[4];
    const float* wd  = (const float*)d_in[5];
    const float* db  = (const float*)d_in[6];

    float* out    = (float*)d_out;
    float* scores = out + (size_t)T_TOK * H_DIM;

    char* ws = (char*)d_ws;
    char* xbuf = ws;                       // 64 MB granule-packed bf16
    size_t off = (size_t)E_EXP * CAP * H_DIM * 2;
    char* act  = ws + off;    off += (size_t)E_EXP * CAP * H_DIM * 2;   // 64 MB
    ushort* eout = (ushort*)(ws + off); off += (size_t)E_EXP * CAP * H_DIM * 2; // 64 MB
    int*   flat_e     = (int*)(ws + off);   off += PAIRS * 4;
    float* flat_w     = (float*)(ws + off); off += PAIRS * 4;
    int*   slot_token = (int*)(ws + off);   off += E_EXP * CAP * 4;
    float* slot_w     = (float*)(ws + off); off += E_EXP * CAP * 4;
    int*   pair_slot  = (int*)(ws + off);   off += PAIRS * 4;
    int*   counts     = (int*)(ws + off);   off += E_EXP * 4;
    (void)ws_size; (void)out_size; (void)n_in; (void)in_sizes; (void)slot_w;

    hipLaunchKernelGGL(router_kernel, dim3(T_TOK / 8), dim3(256), 0, stream,
                       x, rw, rb, scores, flat_e, flat_w);
    hipLaunchKernelGGL(scan_kernel, dim3(1), dim3(256), 0, stream,
                       flat_e, flat_w, slot_token, slot_w, pair_slot, counts);
    hipLaunchKernelGGL(stage_tokens, dim3(8, E_EXP), dim3(256), 0, stream,
                       x, slot_token, counts, xbuf);
    hipLaunchKernelGGL(gateup_mfma, dim3(4096), dim3(256), 0, stream,
                       xbuf, wgu, gub, counts, act);
    hipLaunchKernelGGL(down_mfma, dim3(2048), dim3(256), 0, stream,
                       act, wd, db, counts, eout);
    hipLaunchKernelGGL(finalize_kernel, dim3(T_TOK), dim3(256), 0, stream,
                       eout, flat_e, flat_w, pair_slot, out);
}

// Round 16
// 438.497 us; speedup vs baseline: 1.0473x; 1.0473x over previous
//
#include <hip/hip_runtime.h>
#include <hip/hip_bf16.h>

#define T_TOK 4096
#define H_DIM 1024
#define E_EXP 32
#define TOPK 4
#define CAP 1024
#define PAIRS (T_TOK*TOPK)

typedef __attribute__((ext_vector_type(8))) short short8v;
typedef __attribute__((ext_vector_type(4))) float f32x4;
typedef unsigned long long u64;
typedef unsigned short ushort;

__device__ __forceinline__ float bf16_bits_to_f32(ushort h) {
    return __uint_as_float(((unsigned)h) << 16);
}
__device__ __forceinline__ unsigned bf16r(float f) {
    unsigned u = __float_as_uint(f);
    return ((u + 0x7fffu + ((u >> 16) & 1u)) >> 16) & 0xffffu;
}
__device__ __forceinline__ unsigned cvt2(float a, float b) {
    unsigned r;
    asm("v_cvt_pk_bf16_f32 %0, %1, %2" : "=v"(r) : "v"(a), "v"(b));
    return r;
}
__device__ __forceinline__ u64 pk4(float a, float b, float c, float d) {
    return (u64)cvt2(a, b) | ((u64)cvt2(c, d) << 32);
}

#define GLD16(gsrc, ldst) \
    __builtin_amdgcn_global_load_lds( \
        (const __attribute__((address_space(1))) unsigned*)(gsrc), \
        (__attribute__((address_space(3))) unsigned*)(ldst), 16, 0, 0)

#define WAIT_VM(N)   asm volatile("s_waitcnt vmcnt(" #N ")" ::: "memory")
#define WAIT_VMLG(N) asm volatile("s_waitcnt vmcnt(" #N ") lgkmcnt(0)" ::: "memory")
#define WAIT_LG()    asm volatile("s_waitcnt lgkmcnt(0)" ::: "memory")
#define SCHEDB()     __builtin_amdgcn_sched_barrier(0)
#define BARRIER()    __builtin_amdgcn_s_barrier()

// ---------------- router: 8 tokens/block, single rw pass ----------------
__global__ __launch_bounds__(256) void router_kernel(
    const float* __restrict__ x, const float* __restrict__ rw,
    const float* __restrict__ rb, float* __restrict__ scores,
    int* __restrict__ flat_e, float* __restrict__ flat_w)
{
    __shared__ float xs[8][H_DIM];   // 32 KB
    __shared__ float lg[8][E_EXP];
    const int t0 = blockIdx.x * 8;
    const int tid = threadIdx.x;

    for (int i = tid; i < 2048; i += 256) {
        int row = i >> 8, c4 = i & 255;
        *(float4*)&xs[row][c4 * 4] =
            *(const float4*)(x + (size_t)(t0 + row) * H_DIM + c4 * 4);
    }
    __syncthreads();

    const int e = tid >> 3, l8 = tid & 7;
    float part[8];
    #pragma unroll
    for (int tt = 0; tt < 8; ++tt) part[tt] = 0.f;
    const float* wrow = rw + (size_t)e * H_DIM;
    for (int h = l8; h < H_DIM; h += 8) {
        float w = wrow[h];
        #pragma unroll
        for (int tt = 0; tt < 8; ++tt) part[tt] = fmaf(xs[tt][h], w, part[tt]);
    }
    #pragma unroll
    for (int tt = 0; tt < 8; ++tt) {
        float v = part[tt];
        v += __shfl_xor(v, 1);
        v += __shfl_xor(v, 2);
        v += __shfl_xor(v, 4);
        if (l8 == 0) lg[tt][e] = v + rb[e];
    }
    __syncthreads();

    if (tid < 8) {
        const int tt = tid, t = t0 + tt;
        unsigned used = 0;
        float bv[TOPK]; int bi[TOPK];
        #pragma unroll
        for (int j = 0; j < TOPK; j++) {
            float best = -1e30f; int bid = -1;
            for (int q = 0; q < E_EXP; q++) {
                if (used & (1u << q)) continue;
                if (lg[tt][q] > best) { best = lg[tt][q]; bid = q; }
            }
            used |= 1u << bid;
            bv[j] = best; bi[j] = bid;
        }
        const float m = bv[0];
        float s = 0.f; float w[TOPK];
        #pragma unroll
        for (int j = 0; j < TOPK; j++) { w[j] = expf(bv[j] - m); s += w[j]; }
        const float inv = 1.f / s;
        #pragma unroll
        for (int j = 0; j < TOPK; j++) w[j] *= inv;
        for (int q = 0; q < E_EXP; ++q) {
            float v = 0.f;
            #pragma unroll
            for (int j = 0; j < TOPK; j++) if (bi[j] == q) v = w[j];
            scores[(size_t)t * E_EXP + q] = v;
        }
        #pragma unroll
        for (int j = 0; j < TOPK; j++) {
            flat_e[t * TOPK + j] = bi[j];
            flat_w[t * TOPK + j] = w[j];
        }
    }
}

// ---------------- deterministic rank scan ----------------
__global__ __launch_bounds__(256) void scan_kernel(
    const int* __restrict__ flat_e, const float* __restrict__ flat_w,
    int* __restrict__ slot_token, float* __restrict__ slot_w,
    int* __restrict__ pair_slot, int* __restrict__ counts)
{
    __shared__ int cnt[256 * E_EXP];
    const int tid = threadIdx.x;
    for (int e = 0; e < E_EXP; e++) cnt[tid * E_EXP + e] = 0;
    __syncthreads();
    const int base = tid * (PAIRS / 256);
    for (int i = 0; i < PAIRS / 256; i++) {
        int e = flat_e[base + i];
        cnt[tid * E_EXP + e]++;
    }
    __syncthreads();
    if (tid < E_EXP) {
        int run = 0;
        for (int i = 0; i < 256; i++) {
            int idx = i * E_EXP + tid;
            int v = cnt[idx];
            cnt[idx] = run;
            run += v;
        }
        counts[tid] = min(run, CAP);
    }
    __syncthreads();
    for (int i = 0; i < PAIRS / 256; i++) {
        int p = base + i;
        int e = flat_e[p];
        int r = cnt[tid * E_EXP + e]++;
        if (r < CAP) {
            slot_token[e * CAP + r] = p >> 2;
            slot_w[e * CAP + r] = flat_w[p];
            pair_slot[p] = r;
        } else {
            pair_slot[p] = -1;
        }
    }
}

// ---------------- stage tokens: gather x -> granule-packed bf16 xbuf ----------------
__global__ __launch_bounds__(256) void stage_tokens(
    const float* __restrict__ x, const int* __restrict__ slot_token,
    const int* __restrict__ counts, char* __restrict__ xbuf)
{
    const int e = blockIdx.y, rt = blockIdx.x;
    const int n = counts[e];
    const int row0 = rt * 128;
    if (row0 >= n) return;
    const int rows_here = min(128, n - row0);
    const int lane = threadIdx.x & 63, wv = threadIdx.x >> 6;
    char* tb = xbuf + ((size_t)(e * 8 + rt)) * 262144;

    for (int r = wv; r < rows_here; r += 4) {
        const float* xr = x + (size_t)slot_token[e * CAP + row0 + r] * H_DIM;
        const int s = (r >> 1) & 3;
        #pragma unroll
        for (int half = 0; half < 2; ++half) {
            int gi = half * 64 + lane;
            float4 a = *(const float4*)(xr + gi * 8);
            float4 b = *(const float4*)(xr + gi * 8 + 4);
            uint4 w;
            w.x = cvt2(a.x, a.y); w.y = cvt2(a.z, a.w);
            w.z = cvt2(b.x, b.y); w.w = cvt2(b.z, b.w);
            int t = gi >> 2, kq = gi & 3;
            *(uint4*)(tb + (size_t)t * 8192 + r * 64 + ((kq ^ s) * 16)) = w;
        }
    }
}

// ---------------- gate_up MFMA GEMM: A depth-3 LDS, B depth-3 regs ----------------
__global__ __launch_bounds__(256, 3) void gateup_mfma(
    const char* __restrict__ xbuf, const float* __restrict__ wgu,
    const float* __restrict__ gub, const int* __restrict__ counts,
    char* __restrict__ act)
{
    const int lin = blockIdx.x;
    const int xcd = lin & 7, slot = lin >> 3;
    const int gg = (slot >> 3) * 8 + xcd;
    const int rt = slot & 7;
    const int e = gg >> 4, ct = gg & 15;

    const int n = counts[e];
    const int row0 = rt * 128;
    if (row0 >= n) return;
    const int rows_here = min(128, n - row0);
    const int c0f = ct * 64, c0gu = ct * 128;

    __shared__ char AsB[3][8192];
    __shared__ char BgB[2][4096];
    __shared__ char BuB[2][4096];

    const int tid = threadIdx.x;
    const int lane = tid & 63, wid = tid >> 6;
    const int wr = wid >> 1, wc = wid & 1;
    const int l15 = lane & 15, l4 = lane >> 4;
    const int kq = tid >> 5;      // 0..7 (4-row K group)
    const int p2 = tid & 31;      // gu-col quad index

    const char* xtile = xbuf + ((size_t)(e * 8 + rt)) * 262144;

    f32x4 accg[4][2], accu[4][2];
    #pragma unroll
    for (int m = 0; m < 4; m++)
        #pragma unroll
        for (int j = 0; j < 2; j++) { accg[m][j] = (f32x4)0.f; accu[m][j] = (f32x4)0.f; }

    float4 bv0[4], bv1[4], bv2[4];

#define GU_STAGE_A(BUF, T) { \
    const char* sa_ = xtile + (size_t)(T) * 8192 + tid * 16; \
    GLD16(sa_, AsB[BUF] + tid * 16); \
    GLD16(sa_ + 4096, AsB[BUF] + 4096 + tid * 16); }

#define GU_BLOAD(BV, T) { \
    const float* sb_ = wgu + ((size_t)e * 1024 + (T) * 32 + kq * 4) * 2048 + c0gu + 4 * p2; \
    BV[0] = *(const float4*)(sb_); \
    BV[1] = *(const float4*)(sb_ + 2048); \
    BV[2] = *(const float4*)(sb_ + 4096); \
    BV[3] = *(const float4*)(sb_ + 6144); }

#define GU_BPACK(BUF, BV) { \
    char* dg_ = BgB[BUF] + (kq >> 1) * 1024 + (2 * p2) * 16 + (kq & 1) * 8; \
    char* du_ = BuB[BUF] + (kq >> 1) * 1024 + (2 * p2) * 16 + (kq & 1) * 8; \
    *(u64*)dg_        = pk4(BV[0].x, BV[1].x, BV[2].x, BV[3].x); \
    *(u64*)(dg_ + 16) = pk4(BV[0].z, BV[1].z, BV[2].z, BV[3].z); \
    *(u64*)du_        = pk4(BV[0].y, BV[1].y, BV[2].y, BV[3].y); \
    *(u64*)(du_ + 16) = pk4(BV[0].w, BV[1].w, BV[2].w, BV[3].w); }

#define GU_COMPUTE(AC, BC) { \
    short8v afr[4]; \
    _Pragma("unroll") \
    for (int m = 0; m < 4; ++m) { \
        int row_ = wr * 64 + m * 16 + l15; \
        afr[m] = *(short8v*)(AsB[AC] + row_ * 64 + ((l4 ^ ((row_ >> 1) & 3)) * 16)); \
    } \
    __builtin_amdgcn_s_setprio(1); \
    _Pragma("unroll") \
    for (int j = 0; j < 2; ++j) { \
        int fl_ = wc * 32 + j * 16 + l15; \
        short8v bg8 = *(short8v*)(BgB[BC] + l4 * 1024 + fl_ * 16); \
        short8v bu8 = *(short8v*)(BuB[BC] + l4 * 1024 + fl_ * 16); \
        _Pragma("unroll") \
        for (int m = 0; m < 4; ++m) { \
            accg[m][j] = __builtin_amdgcn_mfma_f32_16x16x32_bf16(afr[m], bg8, accg[m][j], 0, 0, 0); \
            accu[m][j] = __builtin_amdgcn_mfma_f32_16x16x32_bf16(afr[m], bu8, accu[m][j], 0, 0, 0); \
        } \
    } \
    __builtin_amdgcn_s_setprio(0); }

    // prologue: queue = A0[2] B0[4] B1[4] A1[2] B2[4]
    GU_STAGE_A(0, 0);
    GU_BLOAD(bv0, 0);
    GU_BLOAD(bv1, 1);
    GU_STAGE_A(1, 1);
    GU_BLOAD(bv2, 2);
    WAIT_VM(10); SCHEDB();        // drain A0+B0
    GU_BPACK(0, bv0);
    WAIT_LG(); SCHEDB();
    BARRIER(); SCHEDB();

#define GU_IT(T, A2, LS, PS, AC, BC, BN) { \
    GU_STAGE_A(A2, (T) + 2); \
    GU_BLOAD(bv##LS, (T) + 3); \
    GU_COMPUTE(AC, BC); SCHEDB(); \
    WAIT_VM(12); SCHEDB(); \
    GU_BPACK(BN, bv##PS); \
    WAIT_VMLG(10); SCHEDB(); \
    BARRIER(); SCHEDB(); }

    for (int t6 = 0; t6 < 24; t6 += 6) {
        GU_IT(t6 + 0, 2, 0, 1, 0, 0, 1)
        GU_IT(t6 + 1, 0, 1, 2, 1, 1, 0)
        GU_IT(t6 + 2, 1, 2, 0, 2, 0, 1)
        GU_IT(t6 + 3, 2, 0, 1, 0, 1, 0)
        GU_IT(t6 + 4, 0, 1, 2, 1, 0, 1)
        GU_IT(t6 + 5, 1, 2, 0, 2, 1, 0)
    }
    GU_IT(24, 2, 0, 1, 0, 0, 1)
    GU_IT(25, 0, 1, 2, 1, 1, 0)
    GU_IT(26, 1, 2, 0, 2, 0, 1)
    GU_IT(27, 2, 0, 1, 0, 1, 0)
    GU_IT(28, 0, 1, 2, 1, 0, 1)
    // t = 29: stage A(31); no bload
    GU_STAGE_A(1, 31);
    GU_COMPUTE(2, 1); SCHEDB();
    WAIT_VM(8); SCHEDB();
    GU_BPACK(0, bv0);
    WAIT_VMLG(6); SCHEDB();
    BARRIER(); SCHEDB();
    // t = 30
    GU_COMPUTE(0, 0); SCHEDB();
    WAIT_VM(2); SCHEDB();
    GU_BPACK(1, bv1);
    WAIT_VMLG(0); SCHEDB();
    BARRIER(); SCHEDB();
    // t = 31
    GU_COMPUTE(1, 1);

#undef GU_IT
#undef GU_COMPUTE
#undef GU_BPACK
#undef GU_BLOAD
#undef GU_STAGE_A

    // epilogue: bias + clamp + GLU -> act (granule-packed, k-dim = f)
    char* atile = act + ((size_t)(e * 8 + rt)) * 262144;
    #pragma unroll
    for (int j = 0; j < 2; ++j) {
        int f = c0f + wc * 32 + j * 16 + l15;
        float bgb = gub[(size_t)e * 2048 + 2 * f];
        float bub = gub[(size_t)e * 2048 + 2 * f + 1];
        int tt = f >> 5, kq2 = (f & 31) >> 3, ke = f & 7;
        #pragma unroll
        for (int m = 0; m < 4; ++m) {
            int rbase = wr * 64 + m * 16 + l4 * 4;
            #pragma unroll
            for (int reg = 0; reg < 4; ++reg) {
                int r = rbase + reg;
                if (r >= rows_here) continue;
                float g = accg[m][j][reg] + bgb;
                float u = accu[m][j][reg] + bub;
                g = fminf(g, 7.0f);
                u = fminf(fmaxf(u, -7.0f), 7.0f);
                float glu = g / (1.0f + __expf(-1.702f * g));
                float a = (u + 1.0f) * glu;
                *(ushort*)(atile + (size_t)tt * 8192 + r * 64 +
                           ((kq2 ^ ((r >> 1) & 3)) * 16) + ke * 2) = (ushort)bf16r(a);
            }
        }
    }
}

// ---------------- down MFMA GEMM: A depth-3, B depth-3 -> eout (bf16) ----------------
__global__ __launch_bounds__(256, 3) void down_mfma(
    const char* __restrict__ act, const float* __restrict__ wd,
    const float* __restrict__ db, const int* __restrict__ counts,
    ushort* __restrict__ eout)
{
    const int lin = blockIdx.x;
    const int xcd = lin & 7, slot = lin >> 3;
    const int gg = (slot >> 3) * 8 + xcd;
    const int rt = slot & 7;
    const int e = gg >> 3, ct = gg & 7;

    const int n = counts[e];
    const int row0 = rt * 128;
    if (row0 >= n) return;
    const int rows_here = min(128, n - row0);
    const int c0 = ct * 128;

    __shared__ char AsB[3][8192];
    __shared__ char BsB[2][8192];

    const int tid = threadIdx.x;
    const int lane = tid & 63, wid = tid >> 6;
    const int wr = wid >> 1, wc = wid & 1;
    const int l15 = lane & 15, l4 = lane >> 4;
    const int kq = tid >> 5;      // 0..7
    const int p2 = tid & 31;      // n-col quad index

    const char* atile = act + ((size_t)(e * 8 + rt)) * 262144;

    f32x4 acc[4][4];
    #pragma unroll
    for (int m = 0; m < 4; m++)
        #pragma unroll
        for (int j = 0; j < 4; j++) acc[m][j] = (f32x4)0.f;

    float4 bv0[4], bv1[4], bv2[4];

#define DN_STAGE_A(BUF, T) { \
    const char* sa_ = atile + (size_t)(T) * 8192 + tid * 16; \
    GLD16(sa_, AsB[BUF] + tid * 16); \
    GLD16(sa_ + 4096, AsB[BUF] + 4096 + tid * 16); }

#define DN_BLOAD(BV, T) { \
    const float* sb_ = wd + ((size_t)e * 1024 + (T) * 32 + kq * 4) * 1024 + c0 + 4 * p2; \
    BV[0] = *(const float4*)(sb_); \
    BV[1] = *(const float4*)(sb_ + 1024); \
    BV[2] = *(const float4*)(sb_ + 2048); \
    BV[3] = *(const float4*)(sb_ + 3072); }

#define DN_BPACK(BUF, BV) { \
    char* d0_ = BsB[BUF] + (kq >> 1) * 2048 + (4 * p2) * 16 + (kq & 1) * 8; \
    *(u64*)d0_        = pk4(BV[0].x, BV[1].x, BV[2].x, BV[3].x); \
    *(u64*)(d0_ + 16) = pk4(BV[0].y, BV[1].y, BV[2].y, BV[3].y); \
    *(u64*)(d0_ + 32) = pk4(BV[0].z, BV[1].z, BV[2].z, BV[3].z); \
    *(u64*)(d0_ + 48) = pk4(BV[0].w, BV[1].w, BV[2].w, BV[3].w); }

#define DN_COMPUTE(AC, BC) { \
    short8v afr[4]; \
    _Pragma("unroll") \
    for (int m = 0; m < 4; ++m) { \
        int row_ = wr * 64 + m * 16 + l15; \
        afr[m] = *(short8v*)(AsB[AC] + row_ * 64 + ((l4 ^ ((row_ >> 1) & 3)) * 16)); \
    } \
    __builtin_amdgcn_s_setprio(1); \
    _Pragma("unroll") \
    for (int j = 0; j < 4; ++j) { \
        int nn_ = wc * 64 + j * 16 + l15; \
        short8v b8 = *(short8v*)(BsB[BC] + l4 * 2048 + nn_ * 16); \
        _Pragma("unroll") \
        for (int m = 0; m < 4; ++m) \
            acc[m][j] = __builtin_amdgcn_mfma_f32_16x16x32_bf16(afr[m], b8, acc[m][j], 0, 0, 0); \
    } \
    __builtin_amdgcn_s_setprio(0); }

    DN_STAGE_A(0, 0);
    DN_BLOAD(bv0, 0);
    DN_BLOAD(bv1, 1);
    DN_STAGE_A(1, 1);
    DN_BLOAD(bv2, 2);
    WAIT_VM(10); SCHEDB();
    DN_BPACK(0, bv0);
    WAIT_LG(); SCHEDB();
    BARRIER(); SCHEDB();

#define DN_IT(T, A2, LS, PS, AC, BC, BN) { \
    DN_STAGE_A(A2, (T) + 2); \
    DN_BLOAD(bv##LS, (T) + 3); \
    DN_COMPUTE(AC, BC); SCHEDB(); \
    WAIT_VM(12); SCHEDB(); \
    DN_BPACK(BN, bv##PS); \
    WAIT_VMLG(10); SCHEDB(); \
    BARRIER(); SCHEDB(); }

    for (int t6 = 0; t6 < 24; t6 += 6) {
        DN_IT(t6 + 0, 2, 0, 1, 0, 0, 1)
        DN_IT(t6 + 1, 0, 1, 2, 1, 1, 0)
        DN_IT(t6 + 2, 1, 2, 0, 2, 0, 1)
        DN_IT(t6 + 3, 2, 0, 1, 0, 1, 0)
        DN_IT(t6 + 4, 0, 1, 2, 1, 0, 1)
        DN_IT(t6 + 5, 1, 2, 0, 2, 1, 0)
    }
    DN_IT(24, 2, 0, 1, 0, 0, 1)
    DN_IT(25, 0, 1, 2, 1, 1, 0)
    DN_IT(26, 1, 2, 0, 2, 0, 1)
    DN_IT(27, 2, 0, 1, 0, 1, 0)
    DN_IT(28, 0, 1, 2, 1, 0, 1)
    // t = 29
    DN_STAGE_A(1, 31);
    DN_COMPUTE(2, 1); SCHEDB();
    WAIT_VM(8); SCHEDB();
    DN_BPACK(0, bv0);
    WAIT_VMLG(6); SCHEDB();
    BARRIER(); SCHEDB();
    // t = 30
    DN_COMPUTE(0, 0); SCHEDB();
    WAIT_VM(2); SCHEDB();
    DN_BPACK(1, bv1);
    WAIT_VMLG(0); SCHEDB();
    BARRIER(); SCHEDB();
    // t = 31
    DN_COMPUTE(1, 1);

#undef DN_IT
#undef DN_COMPUTE
#undef DN_BPACK
#undef DN_BLOAD
#undef DN_STAGE_A

    // epilogue: bias, store bf16 eout rows (streaming, no atomics)
    #pragma unroll
    for (int j = 0; j < 4; ++j) {
        int col = c0 + wc * 64 + j * 16 + l15;
        float bias = db[(size_t)e * H_DIM + col];
        #pragma unroll
        for (int m = 0; m < 4; ++m) {
            int rbase = wr * 64 + m * 16 + l4 * 4;
            #pragma unroll
            for (int reg = 0; reg < 4; ++reg) {
                int r = rbase + reg;
                if (r >= rows_here) continue;
                eout[((size_t)e * CAP + row0 + r) * H_DIM + col] =
                    (ushort)bf16r(acc[m][j][reg] + bias);
            }
        }
    }
}

// ---------------- finalize: out[t] = sum_k w_k * eout[e_k, slot_k] ----------------
__global__ __launch_bounds__(256) void finalize_kernel(
    const ushort* __restrict__ eout, const int* __restrict__ flat_e,
    const float* __restrict__ flat_w, const int* __restrict__ pair_slot,
    float* __restrict__ out)
{
    const int t = blockIdx.x;
    const int c = threadIdx.x * 4;
    float a0 = 0.f, a1 = 0.f, a2 = 0.f, a3 = 0.f;
    #pragma unroll
    for (int k = 0; k < TOPK; ++k) {
        int p = t * TOPK + k;
        int s = pair_slot[p];
        if (s < 0) continue;
        int e = flat_e[p];
        float w = flat_w[p];
        const ushort* row = eout + ((size_t)e * CAP + s) * H_DIM + c;
        ushort4 v = *(const ushort4*)row;
        a0 += w * bf16_bits_to_f32(v.x);
        a1 += w * bf16_bits_to_f32(v.y);
        a2 += w * bf16_bits_to_f32(v.z);
        a3 += w * bf16_bits_to_f32(v.w);
    }
    *(float4*)(out + (size_t)t * H_DIM + c) = make_float4(a0, a1, a2, a3);
}

extern "C" void kernel_launch(void* const* d_in, const int* in_sizes, int n_in,
                              void* d_out, int out_size, void* d_ws, size_t ws_size,
                              hipStream_t stream) {
    const float* x   = (const float*)d_in[0];
    const float* rw  = (const float*)d_in[1];
    const float* rb  = (const float*)d_in[2];
    const float* wgu = (const float*)d_in[3];
    const float* gub = (const float*)d_in[4];
    const float* wd  = (const float*)d_in[5];
    const float* db  = (const float*)d_in[6];

    float* out    = (float*)d_out;
    float* scores = out + (size_t)T_TOK * H_DIM;

    char* ws = (char*)d_ws;
    char* xbuf = ws;                       // 64 MB granule-packed bf16
    size_t off = (size_t)E_EXP * CAP * H_DIM * 2;
    char* act  = ws + off;    off += (size_t)E_EXP * CAP * H_DIM * 2;   // 64 MB
    ushort* eout = (ushort*)(ws + off); off += (size_t)E_EXP * CAP * H_DIM * 2; // 64 MB
    int*   flat_e     = (int*)(ws + off);   off += PAIRS * 4;
    float* flat_w     = (float*)(ws + off); off += PAIRS * 4;
    int*   slot_token = (int*)(ws + off);   off += E_EXP * CAP * 4;
    float* slot_w     = (float*)(ws + off); off += E_EXP * CAP * 4;
    int*   pair_slot  = (int*)(ws + off);   off += PAIRS * 4;
    int*   counts     = (int*)(ws + off);   off += E_EXP * 4;
    (void)ws_size; (void)out_size; (void)n_in; (void)in_sizes; (void)slot_w;

    hipLaunchKernelGGL(router_kernel, dim3(T_TOK / 8), dim3(256), 0, stream,
                       x, rw, rb, scores, flat_e, flat_w);
    hipLaunchKernelGGL(scan_kernel, dim3(1), dim3(256), 0, stream,
                       flat_e, flat_w, slot_token, slot_w, pair_slot, counts);
    hipLaunchKernelGGL(stage_tokens, dim3(8, E_EXP), dim3(256), 0, stream,
                       x, slot_token, counts, xbuf);
    hipLaunchKernelGGL(gateup_mfma, dim3(4096), dim3(256), 0, stream,
                       xbuf, wgu, gub, counts, act);
    hipLaunchKernelGGL(down_mfma, dim3(2048), dim3(256), 0, stream,
                       act, wd, db, counts, eout);
    hipLaunchKernelGGL(finalize_kernel, dim3(T_TOK), dim3(256), 0, stream,
                       eout, flat_e, flat_w, pair_slot, out);
}

// Round 18
// 416.681 us; speedup vs baseline: 1.1021x; 1.0524x over previous
//
#include <hip/hip_runtime.h>
#include <hip/hip_bf16.h>

#define T_TOK 4096
#define H_DIM 1024
#define E_EXP 32
#define TOPK 4
#define CAP 1024
#define PAIRS (T_TOK*TOPK)

typedef __attribute__((ext_vector_type(8))) short short8v;
typedef __attribute__((ext_vector_type(4))) float f32x4;
typedef unsigned long long u64;
typedef unsigned short ushort;

__device__ __forceinline__ float bf16_bits_to_f32(ushort h) {
    return __uint_as_float(((unsigned)h) << 16);
}
__device__ __forceinline__ unsigned bf16r(float f) {
    unsigned u = __float_as_uint(f);
    return ((u + 0x7fffu + ((u >> 16) & 1u)) >> 16) & 0xffffu;
}
__device__ __forceinline__ unsigned cvt2(float a, float b) {
    unsigned r;
    asm("v_cvt_pk_bf16_f32 %0, %1, %2" : "=v"(r) : "v"(a), "v"(b));
    return r;
}
__device__ __forceinline__ u64 pk4(float a, float b, float c, float d) {
    return (u64)cvt2(a, b) | ((u64)cvt2(c, d) << 32);
}

#define GLD16(gsrc, ldst) \
    __builtin_amdgcn_global_load_lds( \
        (const __attribute__((address_space(1))) unsigned*)(gsrc), \
        (__attribute__((address_space(3))) unsigned*)(ldst), 16, 0, 0)

#define WAIT_VM(N)   asm volatile("s_waitcnt vmcnt(" #N ")" ::: "memory")
#define WAIT_VMLG(N) asm volatile("s_waitcnt vmcnt(" #N ") lgkmcnt(0)" ::: "memory")
#define WAIT_LG()    asm volatile("s_waitcnt lgkmcnt(0)" ::: "memory")
#define SCHEDB()     __builtin_amdgcn_sched_barrier(0)
#define BARRIER()    __builtin_amdgcn_s_barrier()

// bank-spread swizzle for 16B granule index (per-granule; involution)
#define BSWZ(G) ((G) ^ (((G) >> 3) & 7))

// ---------------- router: 8 tokens/block, single rw pass ----------------
__global__ __launch_bounds__(256) void router_kernel(
    const float* __restrict__ x, const float* __restrict__ rw,
    const float* __restrict__ rb, float* __restrict__ scores,
    int* __restrict__ flat_e, float* __restrict__ flat_w)
{
    __shared__ float xs[8][H_DIM];   // 32 KB
    __shared__ float lg[8][E_EXP];
    const int t0 = blockIdx.x * 8;
    const int tid = threadIdx.x;

    for (int i = tid; i < 2048; i += 256) {
        int row = i >> 8, c4 = i & 255;
        *(float4*)&xs[row][c4 * 4] =
            *(const float4*)(x + (size_t)(t0 + row) * H_DIM + c4 * 4);
    }
    __syncthreads();

    const int e = tid >> 3, l8 = tid & 7;
    float part[8];
    #pragma unroll
    for (int tt = 0; tt < 8; ++tt) part[tt] = 0.f;
    const float* wrow = rw + (size_t)e * H_DIM;
    for (int h = l8; h < H_DIM; h += 8) {
        float w = wrow[h];
        #pragma unroll
        for (int tt = 0; tt < 8; ++tt) part[tt] = fmaf(xs[tt][h], w, part[tt]);
    }
    #pragma unroll
    for (int tt = 0; tt < 8; ++tt) {
        float v = part[tt];
        v += __shfl_xor(v, 1);
        v += __shfl_xor(v, 2);
        v += __shfl_xor(v, 4);
        if (l8 == 0) lg[tt][e] = v + rb[e];
    }
    __syncthreads();

    if (tid < 8) {
        const int tt = tid, t = t0 + tt;
        unsigned used = 0;
        float bv[TOPK]; int bi[TOPK];
        #pragma unroll
        for (int j = 0; j < TOPK; j++) {
            float best = -1e30f; int bid = -1;
            for (int q = 0; q < E_EXP; q++) {
                if (used & (1u << q)) continue;
                if (lg[tt][q] > best) { best = lg[tt][q]; bid = q; }
            }
            used |= 1u << bid;
            bv[j] = best; bi[j] = bid;
        }
        const float m = bv[0];
        float s = 0.f; float w[TOPK];
        #pragma unroll
        for (int j = 0; j < TOPK; j++) { w[j] = expf(bv[j] - m); s += w[j]; }
        const float inv = 1.f / s;
        #pragma unroll
        for (int j = 0; j < TOPK; j++) w[j] *= inv;
        for (int q = 0; q < E_EXP; ++q) {
            float v = 0.f;
            #pragma unroll
            for (int j = 0; j < TOPK; j++) if (bi[j] == q) v = w[j];
            scores[(size_t)t * E_EXP + q] = v;
        }
        #pragma unroll
        for (int j = 0; j < TOPK; j++) {
            flat_e[t * TOPK + j] = bi[j];
            flat_w[t * TOPK + j] = w[j];
        }
    }
}

// ---------------- deterministic rank scan ----------------
__global__ __launch_bounds__(256) void scan_kernel(
    const int* __restrict__ flat_e, const float* __restrict__ flat_w,
    int* __restrict__ slot_token, float* __restrict__ slot_w,
    int* __restrict__ pair_slot, int* __restrict__ counts)
{
    __shared__ int cnt[256 * E_EXP];
    const int tid = threadIdx.x;
    for (int e = 0; e < E_EXP; e++) cnt[tid * E_EXP + e] = 0;
    __syncthreads();
    const int base = tid * (PAIRS / 256);
    for (int i = 0; i < PAIRS / 256; i++) {
        int e = flat_e[base + i];
        cnt[tid * E_EXP + e]++;
    }
    __syncthreads();
    if (tid < E_EXP) {
        int run = 0;
        for (int i = 0; i < 256; i++) {
            int idx = i * E_EXP + tid;
            int v = cnt[idx];
            cnt[idx] = run;
            run += v;
        }
        counts[tid] = min(run, CAP);
    }
    __syncthreads();
    for (int i = 0; i < PAIRS / 256; i++) {
        int p = base + i;
        int e = flat_e[p];
        int r = cnt[tid * E_EXP + e]++;
        if (r < CAP) {
            slot_token[e * CAP + r] = p >> 2;
            slot_w[e * CAP + r] = flat_w[p];
            pair_slot[p] = r;
        } else {
            pair_slot[p] = -1;
        }
    }
}

// ---------------- stage tokens: gather x -> granule-packed bf16 xbuf ----------------
__global__ __launch_bounds__(256) void stage_tokens(
    const float* __restrict__ x, const int* __restrict__ slot_token,
    const int* __restrict__ counts, char* __restrict__ xbuf)
{
    const int e = blockIdx.y, rt = blockIdx.x;
    const int n = counts[e];
    const int row0 = rt * 128;
    if (row0 >= n) return;
    const int rows_here = min(128, n - row0);
    const int lane = threadIdx.x & 63, wv = threadIdx.x >> 6;
    char* tb = xbuf + ((size_t)(e * 8 + rt)) * 262144;

    for (int r = wv; r < rows_here; r += 4) {
        const float* xr = x + (size_t)slot_token[e * CAP + row0 + r] * H_DIM;
        const int s = (r >> 1) & 3;
        #pragma unroll
        for (int half = 0; half < 2; ++half) {
            int gi = half * 64 + lane;
            float4 a = *(const float4*)(xr + gi * 8);
            float4 b = *(const float4*)(xr + gi * 8 + 4);
            uint4 w;
            w.x = cvt2(a.x, a.y); w.y = cvt2(a.z, a.w);
            w.z = cvt2(b.x, b.y); w.w = cvt2(b.z, b.w);
            int t = gi >> 2, kq = gi & 3;
            *(uint4*)(tb + (size_t)t * 8192 + r * 64 + ((kq ^ s) * 16)) = w;
        }
    }
}

// ---------------- gate_up MFMA GEMM: A depth-3 LDS, B depth-3 regs ----------------
__global__ __launch_bounds__(256, 3) void gateup_mfma(
    const char* __restrict__ xbuf, const float* __restrict__ wgu,
    const float* __restrict__ gub, const int* __restrict__ counts,
    char* __restrict__ act)
{
    const int lin = blockIdx.x;
    const int xcd = lin & 7, slot = lin >> 3;
    const int gg = (slot >> 3) * 8 + xcd;
    const int rt = slot & 7;
    const int e = gg >> 4, ct = gg & 15;

    const int n = counts[e];
    const int row0 = rt * 128;
    if (row0 >= n) return;
    const int rows_here = min(128, n - row0);
    const int c0f = ct * 64, c0gu = ct * 128;

    __shared__ char AsB[3][8192];
    __shared__ char BgB[2][4096];
    __shared__ char BuB[2][4096];

    const int tid = threadIdx.x;
    const int lane = tid & 63, wid = tid >> 6;
    const int wr = wid >> 1, wc = wid & 1;
    const int l15 = lane & 15, l4 = lane >> 4;
    const int kq = tid >> 5;      // 0..7 (4-row K group)
    const int p2 = tid & 31;      // gu-col quad index

    const char* xtile = xbuf + ((size_t)(e * 8 + rt)) * 262144;

    f32x4 accg[4][2], accu[4][2];
    #pragma unroll
    for (int m = 0; m < 4; m++)
        #pragma unroll
        for (int j = 0; j < 2; j++) { accg[m][j] = (f32x4)0.f; accu[m][j] = (f32x4)0.f; }

    float4 bv0[4], bv1[4], bv2[4];

#define GU_STAGE_A(BUF, T) { \
    const char* sa_ = xtile + (size_t)(T) * 8192 + tid * 16; \
    GLD16(sa_, AsB[BUF] + tid * 16); \
    GLD16(sa_ + 4096, AsB[BUF] + 4096 + tid * 16); }

#define GU_BLOAD(BV, T) { \
    const float* sb_ = wgu + ((size_t)e * 1024 + (T) * 32 + kq * 4) * 2048 + c0gu + 4 * p2; \
    BV[0] = *(const float4*)(sb_); \
    BV[1] = *(const float4*)(sb_ + 2048); \
    BV[2] = *(const float4*)(sb_ + 4096); \
    BV[3] = *(const float4*)(sb_ + 6144); }

// per-granule swizzle: f-col 2p2 -> f0_, f-col 2p2+1 -> f0_^1 (same 8-group)
#define GU_BPACK(BUF, BV) { \
    const int f0_ = BSWZ(2 * p2); \
    char* bg_ = BgB[BUF] + (kq >> 1) * 1024 + (kq & 1) * 8; \
    char* bu_ = BuB[BUF] + (kq >> 1) * 1024 + (kq & 1) * 8; \
    *(u64*)(bg_ + f0_ * 16)        = pk4(BV[0].x, BV[1].x, BV[2].x, BV[3].x); \
    *(u64*)(bg_ + (f0_ ^ 1) * 16)  = pk4(BV[0].z, BV[1].z, BV[2].z, BV[3].z); \
    *(u64*)(bu_ + f0_ * 16)        = pk4(BV[0].y, BV[1].y, BV[2].y, BV[3].y); \
    *(u64*)(bu_ + (f0_ ^ 1) * 16)  = pk4(BV[0].w, BV[1].w, BV[2].w, BV[3].w); }

#define GU_COMPUTE(AC, BC) { \
    short8v afr[4]; \
    _Pragma("unroll") \
    for (int m = 0; m < 4; ++m) { \
        int row_ = wr * 64 + m * 16 + l15; \
        afr[m] = *(short8v*)(AsB[AC] + row_ * 64 + ((l4 ^ ((row_ >> 1) & 3)) * 16)); \
    } \
    __builtin_amdgcn_s_setprio(1); \
    _Pragma("unroll") \
    for (int j = 0; j < 2; ++j) { \
        int fl_ = wc * 32 + j * 16 + l15; \
        int fss_ = BSWZ(fl_); \
        short8v bg8 = *(short8v*)(BgB[BC] + l4 * 1024 + fss_ * 16); \
        short8v bu8 = *(short8v*)(BuB[BC] + l4 * 1024 + fss_ * 16); \
        _Pragma("unroll") \
        for (int m = 0; m < 4; ++m) { \
            accg[m][j] = __builtin_amdgcn_mfma_f32_16x16x32_bf16(afr[m], bg8, accg[m][j], 0, 0, 0); \
            accu[m][j] = __builtin_amdgcn_mfma_f32_16x16x32_bf16(afr[m], bu8, accu[m][j], 0, 0, 0); \
        } \
    } \
    __builtin_amdgcn_s_setprio(0); }

    // prologue: queue = A0[2] B0[4] B1[4] A1[2] B2[4]
    GU_STAGE_A(0, 0);
    GU_BLOAD(bv0, 0);
    GU_BLOAD(bv1, 1);
    GU_STAGE_A(1, 1);
    GU_BLOAD(bv2, 2);
    WAIT_VM(10); SCHEDB();        // drain A0+B0
    GU_BPACK(0, bv0);
    WAIT_LG(); SCHEDB();
    BARRIER(); SCHEDB();

#define GU_IT(T, A2, LS, PS, AC, BC, BN) { \
    GU_STAGE_A(A2, (T) + 2); \
    GU_BLOAD(bv##LS, (T) + 3); \
    GU_COMPUTE(AC, BC); SCHEDB(); \
    WAIT_VM(12); SCHEDB(); \
    GU_BPACK(BN, bv##PS); \
    WAIT_VMLG(10); SCHEDB(); \
    BARRIER(); SCHEDB(); }

    for (int t6 = 0; t6 < 24; t6 += 6) {
        GU_IT(t6 + 0, 2, 0, 1, 0, 0, 1)
        GU_IT(t6 + 1, 0, 1, 2, 1, 1, 0)
        GU_IT(t6 + 2, 1, 2, 0, 2, 0, 1)
        GU_IT(t6 + 3, 2, 0, 1, 0, 1, 0)
        GU_IT(t6 + 4, 0, 1, 2, 1, 0, 1)
        GU_IT(t6 + 5, 1, 2, 0, 2, 1, 0)
    }
    GU_IT(24, 2, 0, 1, 0, 0, 1)
    GU_IT(25, 0, 1, 2, 1, 1, 0)
    GU_IT(26, 1, 2, 0, 2, 0, 1)
    GU_IT(27, 2, 0, 1, 0, 1, 0)
    GU_IT(28, 0, 1, 2, 1, 0, 1)
    // t = 29: stage A(31); no bload
    GU_STAGE_A(1, 31);
    GU_COMPUTE(2, 1); SCHEDB();
    WAIT_VM(8); SCHEDB();
    GU_BPACK(0, bv0);
    WAIT_VMLG(6); SCHEDB();
    BARRIER(); SCHEDB();
    // t = 30
    GU_COMPUTE(0, 0); SCHEDB();
    WAIT_VM(2); SCHEDB();
    GU_BPACK(1, bv1);
    WAIT_VMLG(0); SCHEDB();
    BARRIER(); SCHEDB();
    // t = 31
    GU_COMPUTE(1, 1);

#undef GU_IT
#undef GU_COMPUTE
#undef GU_BPACK
#undef GU_BLOAD
#undef GU_STAGE_A

    // epilogue: bias + clamp + GLU -> act (granule-packed, k-dim = f)
    char* atile = act + ((size_t)(e * 8 + rt)) * 262144;
    #pragma unroll
    for (int j = 0; j < 2; ++j) {
        int f = c0f + wc * 32 + j * 16 + l15;
        float bgb = gub[(size_t)e * 2048 + 2 * f];
        float bub = gub[(size_t)e * 2048 + 2 * f + 1];
        int tt = f >> 5, kq2 = (f & 31) >> 3, ke = f & 7;
        #pragma unroll
        for (int m = 0; m < 4; ++m) {
            int rbase = wr * 64 + m * 16 + l4 * 4;
            #pragma unroll
            for (int reg = 0; reg < 4; ++reg) {
                int r = rbase + reg;
                if (r >= rows_here) continue;
                float g = accg[m][j][reg] + bgb;
                float u = accu[m][j][reg] + bub;
                g = fminf(g, 7.0f);
                u = fminf(fmaxf(u, -7.0f), 7.0f);
                float glu = g / (1.0f + __expf(-1.702f * g));
                float a = (u + 1.0f) * glu;
                *(ushort*)(atile + (size_t)tt * 8192 + r * 64 +
                           ((kq2 ^ ((r >> 1) & 3)) * 16) + ke * 2) = (ushort)bf16r(a);
            }
        }
    }
}

// ---------------- down MFMA GEMM: A depth-3, B depth-3 -> eout (bf16) ----------------
__global__ __launch_bounds__(256, 3) void down_mfma(
    const char* __restrict__ act, const float* __restrict__ wd,
    const float* __restrict__ db, const int* __restrict__ counts,
    ushort* __restrict__ eout)
{
    const int lin = blockIdx.x;
    const int xcd = lin & 7, slot = lin >> 3;
    const int gg = (slot >> 3) * 8 + xcd;
    const int rt = slot & 7;
    const int e = gg >> 3, ct = gg & 7;

    const int n = counts[e];
    const int row0 = rt * 128;
    if (row0 >= n) return;
    const int rows_here = min(128, n - row0);
    const int c0 = ct * 128;

    __shared__ char AsB[3][8192];
    __shared__ char BsB[2][8192];

    const int tid = threadIdx.x;
    const int lane = tid & 63, wid = tid >> 6;
    const int wr = wid >> 1, wc = wid & 1;
    const int l15 = lane & 15, l4 = lane >> 4;
    const int kq = tid >> 5;      // 0..7
    const int p2 = tid & 31;      // n-col quad index

    const char* atile = act + ((size_t)(e * 8 + rt)) * 262144;

    f32x4 acc[4][4];
    #pragma unroll
    for (int m = 0; m < 4; m++)
        #pragma unroll
        for (int j = 0; j < 4; j++) acc[m][j] = (f32x4)0.f;

    float4 bv0[4], bv1[4], bv2[4];

#define DN_STAGE_A(BUF, T) { \
    const char* sa_ = atile + (size_t)(T) * 8192 + tid * 16; \
    GLD16(sa_, AsB[BUF] + tid * 16); \
    GLD16(sa_ + 4096, AsB[BUF] + 4096 + tid * 16); }

#define DN_BLOAD(BV, T) { \
    const float* sb_ = wd + ((size_t)e * 1024 + (T) * 32 + kq * 4) * 1024 + c0 + 4 * p2; \
    BV[0] = *(const float4*)(sb_); \
    BV[1] = *(const float4*)(sb_ + 1024); \
    BV[2] = *(const float4*)(sb_ + 2048); \
    BV[3] = *(const float4*)(sb_ + 3072); }

// per-granule swizzle: n-col 4p2+i -> n0_^i (same 8-group since 4p2%8 in {0,4})
#define DN_BPACK(BUF, BV) { \
    const int n0_ = BSWZ(4 * p2); \
    char* db_ = BsB[BUF] + (kq >> 1) * 2048 + (kq & 1) * 8; \
    *(u64*)(db_ + (n0_    ) * 16) = pk4(BV[0].x, BV[1].x, BV[2].x, BV[3].x); \
    *(u64*)(db_ + (n0_ ^ 1) * 16) = pk4(BV[0].y, BV[1].y, BV[2].y, BV[3].y); \
    *(u64*)(db_ + (n0_ ^ 2) * 16) = pk4(BV[0].z, BV[1].z, BV[2].z, BV[3].z); \
    *(u64*)(db_ + (n0_ ^ 3) * 16) = pk4(BV[0].w, BV[1].w, BV[2].w, BV[3].w); }

#define DN_COMPUTE(AC, BC) { \
    short8v afr[4]; \
    _Pragma("unroll") \
    for (int m = 0; m < 4; ++m) { \
        int row_ = wr * 64 + m * 16 + l15; \
        afr[m] = *(short8v*)(AsB[AC] + row_ * 64 + ((l4 ^ ((row_ >> 1) & 3)) * 16)); \
    } \
    __builtin_amdgcn_s_setprio(1); \
    _Pragma("unroll") \
    for (int j = 0; j < 4; ++j) { \
        int nn_ = wc * 64 + j * 16 + l15; \
        int nss_ = BSWZ(nn_); \
        short8v b8 = *(short8v*)(BsB[BC] + l4 * 2048 + nss_ * 16); \
        _Pragma("unroll") \
        for (int m = 0; m < 4; ++m) \
            acc[m][j] = __builtin_amdgcn_mfma_f32_16x16x32_bf16(afr[m], b8, acc[m][j], 0, 0, 0); \
    } \
    __builtin_amdgcn_s_setprio(0); }

    DN_STAGE_A(0, 0);
    DN_BLOAD(bv0, 0);
    DN_BLOAD(bv1, 1);
    DN_STAGE_A(1, 1);
    DN_BLOAD(bv2, 2);
    WAIT_VM(10); SCHEDB();
    DN_BPACK(0, bv0);
    WAIT_LG(); SCHEDB();
    BARRIER(); SCHEDB();

#define DN_IT(T, A2, LS, PS, AC, BC, BN) { \
    DN_STAGE_A(A2, (T) + 2); \
    DN_BLOAD(bv##LS, (T) + 3); \
    DN_COMPUTE(AC, BC); SCHEDB(); \
    WAIT_VM(12); SCHEDB(); \
    DN_BPACK(BN, bv##PS); \
    WAIT_VMLG(10); SCHEDB(); \
    BARRIER(); SCHEDB(); }

    for (int t6 = 0; t6 < 24; t6 += 6) {
        DN_IT(t6 + 0, 2, 0, 1, 0, 0, 1)
        DN_IT(t6 + 1, 0, 1, 2, 1, 1, 0)
        DN_IT(t6 + 2, 1, 2, 0, 2, 0, 1)
        DN_IT(t6 + 3, 2, 0, 1, 0, 1, 0)
        DN_IT(t6 + 4, 0, 1, 2, 1, 0, 1)
        DN_IT(t6 + 5, 1, 2, 0, 2, 1, 0)
    }
    DN_IT(24, 2, 0, 1, 0, 0, 1)
    DN_IT(25, 0, 1, 2, 1, 1, 0)
    DN_IT(26, 1, 2, 0, 2, 0, 1)
    DN_IT(27, 2, 0, 1, 0, 1, 0)
    DN_IT(28, 0, 1, 2, 1, 0, 1)
    // t = 29
    DN_STAGE_A(1, 31);
    DN_COMPUTE(2, 1); SCHEDB();
    WAIT_VM(8); SCHEDB();
    DN_BPACK(0, bv0);
    WAIT_VMLG(6); SCHEDB();
    BARRIER(); SCHEDB();
    // t = 30
    DN_COMPUTE(0, 0); SCHEDB();
    WAIT_VM(2); SCHEDB();
    DN_BPACK(1, bv1);
    WAIT_VMLG(0); SCHEDB();
    BARRIER(); SCHEDB();
    // t = 31
    DN_COMPUTE(1, 1);

#undef DN_IT
#undef DN_COMPUTE
#undef DN_BPACK
#undef DN_BLOAD
#undef DN_STAGE_A

    // epilogue: bias, store bf16 eout rows (streaming, no atomics)
    #pragma unroll
    for (int j = 0; j < 4; ++j) {
        int col = c0 + wc * 64 + j * 16 + l15;
        float bias = db[(size_t)e * H_DIM + col];
        #pragma unroll
        for (int m = 0; m < 4; ++m) {
            int rbase = wr * 64 + m * 16 + l4 * 4;
            #pragma unroll
            for (int reg = 0; reg < 4; ++reg) {
                int r = rbase + reg;
                if (r >= rows_here) continue;
                eout[((size_t)e * CAP + row0 + r) * H_DIM + col] =
                    (ushort)bf16r(acc[m][j][reg] + bias);
            }
        }
    }
}

// ---------------- finalize: out[t] = sum_k w_k * eout[e_k, slot_k] ----------------
__global__ __launch_bounds__(256) void finalize_kernel(
    const ushort* __restrict__ eout, const int* __restrict__ flat_e,
    const float* __restrict__ flat_w, const int* __restrict__ pair_slot,
    float* __restrict__ out)
{
    const int t = blockIdx.x;
    const int c = threadIdx.x * 4;
    float a0 = 0.f, a1 = 0.f, a2 = 0.f, a3 = 0.f;
    #pragma unroll
    for (int k = 0; k < TOPK; ++k) {
        int p = t * TOPK + k;
        int s = pair_slot[p];
        if (s < 0) continue;
        int e = flat_e[p];
        float w = flat_w[p];
        const ushort* row = eout + ((size_t)e * CAP + s) * H_DIM + c;
        ushort4 v = *(const ushort4*)row;
        a0 += w * bf16_bits_to_f32(v.x);
        a1 += w * bf16_bits_to_f32(v.y);
        a2 += w * bf16_bits_to_f32(v.z);
        a3 += w * bf16_bits_to_f32(v.w);
    }
    *(float4*)(out + (size_t)t * H_DIM + c) = make_float4(a0, a1, a2, a3);
}

extern "C" void kernel_launch(void* const* d_in, const int* in_sizes, int n_in,
                              void* d_out, int out_size, void* d_ws, size_t ws_size,
                              hipStream_t stream) {
    const float* x   = (const float*)d_in[0];
    const float* rw  = (const float*)d_in[1];
    const float* rb  = (const float*)d_in[2];
    const float* wgu = (const float*)d_in[3];
    const float* gub = (const float*)d_in[4];
    const float* wd  = (const float*)d_in[5];
    const float* db  = (const float*)d_in[6];

    float* out    = (float*)d_out;
    float* scores = out + (size_t)T_TOK * H_DIM;

    char* ws = (char*)d_ws;
    char* xbuf = ws;                       // 64 MB granule-packed bf16
    size_t off = (size_t)E_EXP * CAP * H_DIM * 2;
    char* act  = ws + off;    off += (size_t)E_EXP * CAP * H_DIM * 2;   // 64 MB
    ushort* eout = (ushort*)(ws + off); off += (size_t)E_EXP * CAP * H_DIM * 2; // 64 MB
    int*   flat_e     = (int*)(ws + off);   off += PAIRS * 4;
    float* flat_w     = (float*)(ws + off); off += PAIRS * 4;
    int*   slot_token = (int*)(ws + off);   off += E_EXP * CAP * 4;
    float* slot_w     = (float*)(ws + off); off += E_EXP * CAP * 4;
    int*   pair_slot  = (int*)(ws + off);   off += PAIRS * 4;
    int*   counts     = (int*)(ws + off);   off += E_EXP * 4;
    (void)ws_size; (void)out_size; (void)n_in; (void)in_sizes; (void)slot_w;

    hipLaunchKernelGGL(router_kernel, dim3(T_TOK / 8), dim3(256), 0, stream,
                       x, rw, rb, scores, flat_e, flat_w);
    hipLaunchKernelGGL(scan_kernel, dim3(1), dim3(256), 0, stream,
                       flat_e, flat_w, slot_token, slot_w, pair_slot, counts);
    hipLaunchKernelGGL(stage_tokens, dim3(8, E_EXP), dim3(256), 0, stream,
                       x, slot_token, counts, xbuf);
    hipLaunchKernelGGL(gateup_mfma, dim3(4096), dim3(256), 0, stream,
                       xbuf, wgu, gub, counts, act);
    hipLaunchKernelGGL(down_mfma, dim3(2048), dim3(256), 0, stream,
                       act, wd, db, counts, eout);
    hipLaunchKernelGGL(finalize_kernel, dim3(T_TOK), dim3(256), 0, stream,
                       eout, flat_e, flat_w, pair_slot, out);
}